// Round 1
// baseline (7406.760 us; speedup 1.0000x reference)
//
#include <hip/hip_runtime.h>

// ---------------------------------------------------------------------------
// MattingSolver CG on MI355X.
// A = Lcm + Lm + Lc + diag_ku,  Lcm = L^T L with L = diag(rs_cm) - Wcm(COO),
// Lm = 9x9 symmetrized stencil blocks, Lc = 5-NN symmetrized affinities.
//
// Per CG iteration (4 kernels, scalars stay on device in ws):
//   k_B: Lv -= Wcm p (scatter); Ap -= (Wm p + Wc p) (scatter);
//        pAp += sum D p^2 - p^T Wm p - p^T Wc p
//   k_C: Ap += rs_cm*Lv - Wcm^T Lv (scatter);  pAp += |Lv|^2
//   k_F: alpha = rs/pAp; x += alpha p; r -= alpha Ap; rs_new = r.r
//   k_G: beta = rs_new/rs; p = r + beta p; Lv = rs_cm*p; Ap = D*p  (next iter)
// pAp assembled via quadratic forms so no extra reduction pass is needed.
// ---------------------------------------------------------------------------

__device__ __forceinline__ float blockReduce256(float v) {
  #pragma unroll
  for (int o = 32; o > 0; o >>= 1) v += __shfl_down(v, o, 64);
  __shared__ float s[4];
  int lane = threadIdx.x & 63;
  int wv   = threadIdx.x >> 6;
  if (lane == 0) s[wv] = v;
  __syncthreads();
  float r = 0.f;
  if (threadIdx.x == 0) r = s[0] + s[1] + s[2] + s[3];
  return r;
}

__global__ void k_init0(const float* __restrict__ KUw, const float* __restrict__ kToUconf,
                        const float* __restrict__ lmbda, const float* __restrict__ known,
                        const float* __restrict__ kToU,
                        float* __restrict__ Dall, float* __restrict__ rs_cm,
                        float* __restrict__ r, float* __restrict__ p, float* __restrict__ x,
                        float* __restrict__ scal, int N)
{
  int i = blockIdx.x * 256 + threadIdx.x;
  if (i < 64) scal[i] = 0.f;
  if (i < N) {
    float dk = KUw[i] * kToUconf[i] + lmbda[0] * known[i];
    Dall[i]  = dk;          // rs_m, rs_c atomically added later
    rs_cm[i] = 0.f;
    float b  = dk * kToU[i];
    r[i] = b; p[i] = b; x[i] = 0.f;
  }
}

__global__ void k_init1(const float* __restrict__ CMw, const float* __restrict__ Wcm_data,
                        const int* __restrict__ Wrow,
                        float* __restrict__ cm_vals, float* __restrict__ rs_cm,
                        const float* __restrict__ LOCw, const float* __restrict__ LOC_flows,
                        const int* __restrict__ LOC_inInd, const int* __restrict__ width_p,
                        const float* __restrict__ IUw, const float* __restrict__ IU_flows,
                        const int* __restrict__ IU_inInd, const int* __restrict__ IU_neighInd,
                        float* __restrict__ Dall,
                        const float* __restrict__ r, float* __restrict__ scal,
                        int NNZ, int NLOC, int N, int B0, int B1, int B2)
{
  int blk = blockIdx.x;
  if (blk < B0) {                       // color-mixture: vals + row sums
    int e = blk * 256 + threadIdx.x;
    if (e < NNZ) {
      int row = Wrow[e];
      float cv = CMw[row] * Wcm_data[e];
      cm_vals[e] = cv;
      atomicAdd(&rs_cm[row], cv);
    }
  } else if (blk < B1) {                // matting stencil row sums -> Dall
    int k = (blk - B0) * 256 + threadIdx.x;
    if (k < NLOC) {
      int wd = *width_p;
      float Fl[81];
      #pragma unroll
      for (int m = 0; m < 81; ++m) Fl[m] = LOC_flows[(size_t)m * NLOC + k];
      int base = LOC_inInd[k];
      float hw = 0.5f * LOCw[base];
      const int offs[9] = {-1 - wd, -1, -1 + wd, -wd, 0, wd, 1 - wd, 1, 1 + wd};
      #pragma unroll
      for (int a = 0; a < 9; ++a) {
        float u = 0.f;
        #pragma unroll
        for (int b = 0; b < 9; ++b) u += Fl[b * 9 + a] + Fl[a * 9 + b];
        atomicAdd(&Dall[base + offs[a]], hw * u);
      }
    }
  } else if (blk < B2) {                // IU KNN row sums -> Dall
    int k = (blk - B1) * 256 + threadIdx.x;
    if (k < NLOC) {
      int r0 = IU_inInd[k];
      float hw = 0.5f * IUw[r0];
      #pragma unroll
      for (int j = 0; j < 5; ++j) {
        float val = hw * IU_flows[k * 5 + j];
        int c0 = IU_neighInd[k * 5 + j];
        atomicAdd(&Dall[r0], val);
        atomicAdd(&Dall[c0], val);
      }
    }
  } else {                              // rs[0] = b.b  (r == b here)
    int i = (blk - B2) * 256 + threadIdx.x;
    float v = 0.f;
    if (i < N) { float b = r[i]; v = b * b; }
    v = blockReduce256(v);
    if (threadIdx.x == 0) atomicAdd(&scal[0], v);
  }
}

__global__ void k_A(const float* __restrict__ p, const float* __restrict__ rs_cm,
                    const float* __restrict__ Dall,
                    float* __restrict__ Lv, float* __restrict__ Ap, int N)
{
  int i = blockIdx.x * 256 + threadIdx.x;
  if (i < N) {
    float pi = p[i];
    Lv[i] = rs_cm[i] * pi;
    Ap[i] = Dall[i] * pi;
  }
}

__global__ void k_B(const float* __restrict__ cm_vals, const int* __restrict__ Wrow,
                    const int* __restrict__ Wcol,
                    const float* __restrict__ p, float* __restrict__ Lv, float* __restrict__ Ap,
                    const float* __restrict__ LOC_flows, const int* __restrict__ LOC_inInd,
                    const float* __restrict__ LOCw, const int* __restrict__ width_p,
                    const float* __restrict__ IU_flows, const int* __restrict__ IU_inInd,
                    const int* __restrict__ IU_neighInd, const float* __restrict__ IUw,
                    const float* __restrict__ Dall, float* __restrict__ pAp_t,
                    int NNZ, int NLOC, int N, int B0, int B1, int B2)
{
  int blk = blockIdx.x;
  if (blk < B0) {                       // Lv -= Wcm p
    int e = blk * 256 + threadIdx.x;
    if (e < NNZ) atomicAdd(&Lv[Wrow[e]], -cm_vals[e] * p[Wcol[e]]);
  } else if (blk < B1) {                // Ap -= Wm p ;  pAp -= p^T Wm p
    int k = (blk - B0) * 256 + threadIdx.x;
    float qf = 0.f;
    if (k < NLOC) {
      int wd = *width_p;
      float Fl[81];
      #pragma unroll
      for (int m = 0; m < 81; ++m) Fl[m] = LOC_flows[(size_t)m * NLOC + k];
      int base = LOC_inInd[k];
      float hw = 0.5f * LOCw[base];
      const int offs[9] = {-1 - wd, -1, -1 + wd, -wd, 0, wd, 1 - wd, 1, 1 + wd};
      int ng[9]; float vv[9];
      #pragma unroll
      for (int a = 0; a < 9; ++a) { ng[a] = base + offs[a]; vv[a] = p[ng[a]]; }
      #pragma unroll
      for (int a = 0; a < 9; ++a) {
        float u = 0.f;
        #pragma unroll
        for (int b = 0; b < 9; ++b) u += (Fl[b * 9 + a] + Fl[a * 9 + b]) * vv[b];
        u *= hw;
        atomicAdd(&Ap[ng[a]], -u);
        qf += u * vv[a];
      }
    }
    qf = blockReduce256(qf);
    if (threadIdx.x == 0) atomicAdd(pAp_t, -qf);
  } else if (blk < B2) {                // Ap -= Wc p ;  pAp -= p^T Wc p
    int k = (blk - B1) * 256 + threadIdx.x;
    float qf = 0.f;
    if (k < NLOC) {
      int r0 = IU_inInd[k];
      float hw = 0.5f * IUw[r0];
      float pr = p[r0];
      #pragma unroll
      for (int j = 0; j < 5; ++j) {
        float val = hw * IU_flows[k * 5 + j];
        int c0 = IU_neighInd[k * 5 + j];
        float pc = p[c0];
        atomicAdd(&Ap[r0], -val * pc);
        atomicAdd(&Ap[c0], -val * pr);
        qf += 2.f * val * pr * pc;
      }
    }
    qf = blockReduce256(qf);
    if (threadIdx.x == 0) atomicAdd(pAp_t, -qf);
  } else {                              // pAp += sum D p^2
    int i = (blk - B2) * 256 + threadIdx.x;
    float v = 0.f;
    if (i < N) { float pi = p[i]; v = Dall[i] * pi * pi; }
    v = blockReduce256(v);
    if (threadIdx.x == 0) atomicAdd(pAp_t, v);
  }
}

__global__ void k_C(const float* __restrict__ cm_vals, const int* __restrict__ Wrow,
                    const int* __restrict__ Wcol,
                    const float* __restrict__ Lv, float* __restrict__ Ap,
                    const float* __restrict__ rs_cm,
                    float* __restrict__ pAp_t, int NNZ, int N, int B0)
{
  int blk = blockIdx.x;
  if (blk < B0) {                       // Ap -= Wcm^T Lv
    int e = blk * 256 + threadIdx.x;
    if (e < NNZ) atomicAdd(&Ap[Wcol[e]], -cm_vals[e] * Lv[Wrow[e]]);
  } else {                              // Ap += rs_cm*Lv ;  pAp += |Lv|^2
    int i = (blk - B0) * 256 + threadIdx.x;
    float v = 0.f;
    if (i < N) { float lv = Lv[i]; atomicAdd(&Ap[i], rs_cm[i] * lv); v = lv * lv; }
    v = blockReduce256(v);
    if (threadIdx.x == 0) atomicAdd(pAp_t, v);
  }
}

__global__ void k_F(float* __restrict__ x, float* __restrict__ r,
                    const float* __restrict__ p, const float* __restrict__ Ap,
                    const float* __restrict__ rs_t, const float* __restrict__ pAp_t,
                    float* __restrict__ rs_t1, int N)
{
  int i = blockIdx.x * 256 + threadIdx.x;
  float alpha = rs_t[0] / pAp_t[0];
  float v = 0.f;
  if (i < N) {
    x[i] += alpha * p[i];
    float rn = r[i] - alpha * Ap[i];
    r[i] = rn;
    v = rn * rn;
  }
  v = blockReduce256(v);
  if (threadIdx.x == 0) atomicAdd(rs_t1, v);
}

__global__ void k_G(float* __restrict__ p, const float* __restrict__ r,
                    const float* __restrict__ rs_cm, const float* __restrict__ Dall,
                    float* __restrict__ Lv, float* __restrict__ Ap,
                    const float* __restrict__ rs_new, const float* __restrict__ rs_old, int N)
{
  int i = blockIdx.x * 256 + threadIdx.x;
  float beta = rs_new[0] / rs_old[0];
  if (i < N) {
    float pn = r[i] + beta * p[i];
    p[i]  = pn;
    Lv[i] = rs_cm[i] * pn;
    Ap[i] = Dall[i] * pn;
  }
}

extern "C" void kernel_launch(void* const* d_in, const int* in_sizes, int n_in,
                              void* d_out, int out_size, void* d_ws, size_t ws_size,
                              hipStream_t stream)
{
  const float* CMw       = (const float*)d_in[0];
  const float* LOCw      = (const float*)d_in[1];
  const float* IUw       = (const float*)d_in[2];
  const float* KUw       = (const float*)d_in[3];
  const float* lmbda     = (const float*)d_in[4];
  const float* kToUconf  = (const float*)d_in[5];
  const float* known     = (const float*)d_in[6];
  const float* kToU      = (const float*)d_in[7];
  const float* Wcm_data  = (const float*)d_in[8];
  const float* LOC_flows = (const float*)d_in[9];
  const float* IU_flows  = (const float*)d_in[10];
  const int*   Wrow      = (const int*)d_in[11];
  const int*   Wcol      = (const int*)d_in[12];
  const int*   LOC_inInd = (const int*)d_in[13];
  const int*   IU_inInd  = (const int*)d_in[14];
  const int*   IU_neighInd = (const int*)d_in[15];
  const int*   width_p   = (const int*)d_in[16];
  const int CG_STEPS = 30;   // host-side structural constant (ref setup)

  const int N    = in_sizes[0];
  const int NNZ  = in_sizes[8];
  const int NLOC = in_sizes[13];

  float* ws      = (float*)d_ws;
  float* x       = (float*)d_out;
  float* r       = ws;
  float* p       = ws + (size_t)N;
  float* Lv      = ws + (size_t)2 * N;
  float* Ap      = ws + (size_t)3 * N;
  float* rs_cm   = ws + (size_t)4 * N;
  float* Dall    = ws + (size_t)5 * N;
  float* cm_vals = ws + (size_t)6 * N;
  float* scal    = ws + (size_t)6 * N + NNZ;  // rs[t] at scal[t], pAp[t] at scal[32+t]

  const int Bn = (N + 255) / 256;
  const int Bz = (NNZ + 255) / 256;
  const int Bl = (NLOC + 255) / 256;

  k_init0<<<Bn, 256, 0, stream>>>(KUw, kToUconf, lmbda, known, kToU,
                                  Dall, rs_cm, r, p, x, scal, N);
  k_init1<<<Bz + Bl + Bl + Bn, 256, 0, stream>>>(
      CMw, Wcm_data, Wrow, cm_vals, rs_cm,
      LOCw, LOC_flows, LOC_inInd, width_p,
      IUw, IU_flows, IU_inInd, IU_neighInd,
      Dall, r, scal, NNZ, NLOC, N, Bz, Bz + Bl, Bz + Bl + Bl);
  k_A<<<Bn, 256, 0, stream>>>(p, rs_cm, Dall, Lv, Ap, N);

  for (int t = 0; t < CG_STEPS; ++t) {
    k_B<<<Bz + Bl + Bl + Bn, 256, 0, stream>>>(
        cm_vals, Wrow, Wcol, p, Lv, Ap,
        LOC_flows, LOC_inInd, LOCw, width_p,
        IU_flows, IU_inInd, IU_neighInd, IUw,
        Dall, scal + 32 + t, NNZ, NLOC, N, Bz, Bz + Bl, Bz + Bl + Bl);
    k_C<<<Bz + Bn, 256, 0, stream>>>(cm_vals, Wrow, Wcol, Lv, Ap, rs_cm,
                                     scal + 32 + t, NNZ, N, Bz);
    k_F<<<Bn, 256, 0, stream>>>(x, r, p, Ap, scal + t, scal + 32 + t, scal + t + 1, N);
    if (t + 1 < CG_STEPS)
      k_G<<<Bn, 256, 0, stream>>>(p, r, rs_cm, Dall, Lv, Ap, scal + t + 1, scal + t, N);
  }
}

// Round 2
// 2697.357 us; speedup vs baseline: 2.7459x; 2.7459x over previous
//
#include <hip/hip_runtime.h>

// ---------------------------------------------------------------------------
// MattingSolver CG on MI355X — round 2: scatter->gather rewrite.
//
// Round-1 evidence: k_B WRITE_SIZE = 89.8 MB/dispatch = 2.95M atomics x ~32B
// write-through (device-scope atomics bypass per-XCD L2). VALUBusy 0.9%.
// Fix: build CSR(Wcm), CSC(Wcm), and a row-grouped gather list for Wm+Wc once
// per launch (counting sort), then run 30 CG iterations with pure gathers.
//
// Per iteration (3 kernels):
//   k_it1: u_all = per-k Wm/Wc products (coalesced flows); Lv = rs_cm*p - Wcm p
//          (CSR gather); pAp = sum D p^2 + |Lv|^2 - p'Wm p - p'Wc p
//   k_it2: Ap_i = D p - gather(u_all) + rs_cm Lv - Wcm^T Lv (CSC gather);
//          alpha = rs/pAp; x += alpha p; r -= alpha Ap; rs_new = r.r
//   k_it3: beta = rs_new/rs; p = r + beta p
// N, NLOC, NNZ are all multiples of 256 -> no tail handling in block ranges.
// ---------------------------------------------------------------------------

#define TPB 256

__device__ __forceinline__ float blockReduce256(float v) {
  #pragma unroll
  for (int o = 32; o > 0; o >>= 1) v += __shfl_down(v, o, 64);
  __shared__ float s[4];
  int lane = threadIdx.x & 63, wv = threadIdx.x >> 6;
  if (lane == 0) s[wv] = v;
  __syncthreads();
  return (threadIdx.x == 0) ? (s[0] + s[1] + s[2] + s[3]) : 0.f;
}

__global__ void k_init0(const float* __restrict__ KUw, const float* __restrict__ kToUconf,
                        const float* __restrict__ lmbda, const float* __restrict__ known,
                        const float* __restrict__ kToU,
                        float* __restrict__ Dall, float* __restrict__ rs_cm,
                        float* __restrict__ r, float* __restrict__ p, float* __restrict__ x,
                        int* __restrict__ CNT, float* __restrict__ scal, int N)
{
  int i = blockIdx.x * TPB + threadIdx.x;
  if (i < 96) scal[i] = 0.f;
  if (i < 3 * N) CNT[i] = 0;
  if (i < N) {
    float dk = KUw[i] * kToUconf[i] + lmbda[0] * known[i];
    Dall[i] = dk;
    rs_cm[i] = 0.f;
    float b = dk * kToU[i];
    r[i] = b; p[i] = b; x[i] = 0.f;
  }
}

__global__ void k_hist(const float* __restrict__ CMw, const float* __restrict__ Wcm_data,
                       const int* __restrict__ Wrow, const int* __restrict__ Wcol,
                       const float* __restrict__ LOCw, const float* __restrict__ LOC_flows,
                       const int* __restrict__ LOC_inInd, const int* __restrict__ width_p,
                       const float* __restrict__ IUw, const float* __restrict__ IU_flows,
                       const int* __restrict__ IU_inInd, const int* __restrict__ IU_neighInd,
                       float* __restrict__ rs_cm, float* __restrict__ Dall,
                       int* __restrict__ CNT, const float* __restrict__ r,
                       float* __restrict__ scal,
                       int NNZ, int NLOC, int N, int B0, int B1, int B2)
{
  int blk = blockIdx.x;
  if (blk < B0) {                       // CM: rowsum + row/col histograms
    int e = blk * TPB + threadIdx.x;
    int row = Wrow[e], col = Wcol[e];
    float cv = CMw[row] * Wcm_data[e];
    atomicAdd(&rs_cm[row], cv);
    atomicAdd(&CNT[row], 1);
    atomicAdd(&CNT[N + col], 1);
  } else if (blk < B1) {                // Wm: row sums -> Dall, counts
    int k = (blk - B0) * TPB + threadIdx.x;
    int wd = *width_p;
    float Fl[81];
    #pragma unroll
    for (int m = 0; m < 81; ++m) Fl[m] = LOC_flows[(size_t)m * NLOC + k];
    int base = LOC_inInd[k];
    float hw = 0.5f * LOCw[base];
    const int offs[9] = {-1 - wd, -1, -1 + wd, -wd, 0, wd, 1 - wd, 1, 1 + wd};
    #pragma unroll
    for (int a = 0; a < 9; ++a) {
      float u = 0.f;
      #pragma unroll
      for (int b = 0; b < 9; ++b) u += Fl[b * 9 + a] + Fl[a * 9 + b];
      atomicAdd(&Dall[base + offs[a]], hw * u);
      atomicAdd(&CNT[2 * N + base + offs[a]], 1);
    }
  } else if (blk < B2) {                // Wc: row sums -> Dall, counts
    int k = (blk - B1) * TPB + threadIdx.x;
    int r0 = IU_inInd[k];
    float hw = 0.5f * IUw[r0];
    #pragma unroll
    for (int j = 0; j < 5; ++j) {
      float val = hw * IU_flows[k * 5 + j];
      int c0 = IU_neighInd[k * 5 + j];
      atomicAdd(&Dall[r0], val);
      atomicAdd(&Dall[c0], val);
      atomicAdd(&CNT[2 * N + r0], 1);
      atomicAdd(&CNT[2 * N + c0], 1);
    }
  } else {                              // rs[0] = b.b
    int i = (blk - B2) * TPB + threadIdx.x;
    float b = r[i];
    float v = blockReduce256(b * b);
    if (threadIdx.x == 0) atomicAdd(&scal[0], v);
  }
}

__global__ void k_scan1(const int* __restrict__ CNT, int* __restrict__ OFF,
                        int* __restrict__ bsum, int tot)
{
  __shared__ int s[TPB];
  int gid = blockIdx.x * TPB + threadIdx.x;
  int v = (gid < tot) ? CNT[gid] : 0;
  s[threadIdx.x] = v;
  __syncthreads();
  #pragma unroll
  for (int o = 1; o < TPB; o <<= 1) {
    int t = (threadIdx.x >= o) ? s[threadIdx.x - o] : 0;
    __syncthreads();
    s[threadIdx.x] += t;
    __syncthreads();
  }
  if (gid < tot) OFF[gid] = s[threadIdx.x] - v;
  if (threadIdx.x == TPB - 1) bsum[blockIdx.x] = s[threadIdx.x];
}

__global__ void k_scan2(int* __restrict__ bsum, int nPerArr)  // 3 blocks x 1024
{
  __shared__ int s[1024];
  int base = blockIdx.x * nPerArr;
  int v = (threadIdx.x < nPerArr) ? bsum[base + threadIdx.x] : 0;
  s[threadIdx.x] = v;
  __syncthreads();
  for (int o = 1; o < 1024; o <<= 1) {
    int t = (threadIdx.x >= o) ? s[threadIdx.x - o] : 0;
    __syncthreads();
    s[threadIdx.x] += t;
    __syncthreads();
  }
  if (threadIdx.x < nPerArr) bsum[base + threadIdx.x] = s[threadIdx.x] - v;
}

__global__ void k_scan3(int* __restrict__ OFF, int* __restrict__ CUR,
                        const int* __restrict__ bsum, int tot)
{
  int gid = blockIdx.x * TPB + threadIdx.x;
  if (gid < tot) {
    int o = OFF[gid] + bsum[blockIdx.x];
    OFF[gid] = o;
    CUR[gid] = o;
  }
}

__global__ void k_fill(const float* __restrict__ CMw, const float* __restrict__ Wcm_data,
                       const int* __restrict__ Wrow, const int* __restrict__ Wcol,
                       const int* __restrict__ LOC_inInd, const int* __restrict__ width_p,
                       const int* __restrict__ IU_inInd, const int* __restrict__ IU_neighInd,
                       int* __restrict__ CUR,
                       int* __restrict__ csr_col, float* __restrict__ csr_val,
                       int* __restrict__ csc_row, float* __restrict__ csc_val,
                       int* __restrict__ gIdx,
                       int NNZ, int NLOC, int N, int B0, int B1)
{
  int blk = blockIdx.x;
  if (blk < B0) {                       // CM entries -> CSR + CSC
    int e = blk * TPB + threadIdx.x;
    int row = Wrow[e], col = Wcol[e];
    float cv = CMw[row] * Wcm_data[e];
    int pr = atomicAdd(&CUR[row], 1);
    csr_col[pr] = col; csr_val[pr] = cv;
    int pc = atomicAdd(&CUR[N + col], 1);
    csc_row[pc] = row; csc_val[pc] = cv;
  } else if (blk < B1) {                // Wm: (k,a) -> row neigh_a
    int k = (blk - B0) * TPB + threadIdx.x;
    int wd = *width_p;
    int base = LOC_inInd[k];
    const int offs[9] = {-1 - wd, -1, -1 + wd, -wd, 0, wd, 1 - wd, 1, 1 + wd};
    #pragma unroll
    for (int a = 0; a < 9; ++a) {
      int pos = atomicAdd(&CUR[2 * N + base + offs[a]], 1);
      gIdx[pos] = a * NLOC + k;
    }
  } else {                              // Wc: two directions per (k,j)
    int k = (blk - B1) * TPB + threadIdx.x;
    int r0 = IU_inInd[k];
    #pragma unroll
    for (int j = 0; j < 5; ++j) {
      int c0 = IU_neighInd[k * 5 + j];
      int p1 = atomicAdd(&CUR[2 * N + r0], 1);
      gIdx[p1] = 9 * NLOC + j * NLOC + k;    // prodA = val*p[c0] -> row r0
      int p2 = atomicAdd(&CUR[2 * N + c0], 1);
      gIdx[p2] = 14 * NLOC + j * NLOC + k;   // prodB = val*p[r0] -> row c0
    }
  }
}

__global__ void k_it1(const float* __restrict__ p,
                      const float* __restrict__ LOC_flows, const int* __restrict__ LOC_inInd,
                      const float* __restrict__ LOCw, const int* __restrict__ width_p,
                      const float* __restrict__ IU_flows, const int* __restrict__ IU_inInd,
                      const int* __restrict__ IU_neighInd, const float* __restrict__ IUw,
                      const float* __restrict__ rs_cm, const float* __restrict__ Dall,
                      const int* __restrict__ OFF,
                      const int* __restrict__ csr_col, const float* __restrict__ csr_val,
                      float* __restrict__ u_all, float* __restrict__ Lv,
                      float* __restrict__ pAp_t,
                      int NNZ, int NLOC, int N, int B0, int B1)
{
  int blk = blockIdx.x;
  float red = 0.f;
  if (blk < B0) {                       // Wm phase A: u[a*NLOC+k], qf_m
    int k = blk * TPB + threadIdx.x;
    int wd = *width_p;
    float Fl[81];
    #pragma unroll
    for (int m = 0; m < 81; ++m) Fl[m] = LOC_flows[(size_t)m * NLOC + k];
    int base = LOC_inInd[k];
    float hw = 0.5f * LOCw[base];
    const int offs[9] = {-1 - wd, -1, -1 + wd, -wd, 0, wd, 1 - wd, 1, 1 + wd};
    float vv[9];
    #pragma unroll
    for (int a = 0; a < 9; ++a) vv[a] = p[base + offs[a]];
    float qf = 0.f;
    #pragma unroll
    for (int a = 0; a < 9; ++a) {
      float u = 0.f;
      #pragma unroll
      for (int b = 0; b < 9; ++b) u += (Fl[b * 9 + a] + Fl[a * 9 + b]) * vv[b];
      u *= hw;
      u_all[a * NLOC + k] = u;
      qf += u * vv[a];
    }
    red = -qf;
  } else if (blk < B1) {                // Wc products, qf_c
    int k = (blk - B0) * TPB + threadIdx.x;
    int r0 = IU_inInd[k];
    float hw = 0.5f * IUw[r0];
    float pr = p[r0];
    float qf = 0.f;
    #pragma unroll
    for (int j = 0; j < 5; ++j) {
      float val = hw * IU_flows[k * 5 + j];
      int c0 = IU_neighInd[k * 5 + j];
      float pc = p[c0];
      u_all[9 * NLOC + j * NLOC + k] = val * pc;
      u_all[14 * NLOC + j * NLOC + k] = val * pr;
      qf += 2.f * val * pr * pc;
    }
    red = -qf;
  } else {                              // CSR gather: Lv, D p^2 + Lv^2
    int i = (blk - B1) * TPB + threadIdx.x;
    float pi = p[i];
    float acc = rs_cm[i] * pi;
    int s = OFF[i];
    int e = (i == N - 1) ? NNZ : OFF[i + 1];
    for (int q = s; q < e; ++q) acc -= csr_val[q] * p[csr_col[q]];
    Lv[i] = acc;
    red = Dall[i] * pi * pi + acc * acc;
  }
  float v = blockReduce256(red);
  if (threadIdx.x == 0) atomicAdd(pAp_t, v);
}

__global__ void k_it2(float* __restrict__ x, float* __restrict__ r,
                      const float* __restrict__ p, const float* __restrict__ Lv,
                      const float* __restrict__ rs_cm, const float* __restrict__ Dall,
                      const int* __restrict__ OFF,
                      const int* __restrict__ csc_row, const float* __restrict__ csc_val,
                      const int* __restrict__ gIdx, const float* __restrict__ u_all,
                      const float* __restrict__ rs_t, const float* __restrict__ pAp_t,
                      float* __restrict__ rs_t1,
                      int NNZ, int NG, int N)
{
  int i = blockIdx.x * TPB + threadIdx.x;
  float alpha = rs_t[0] / pAp_t[0];
  float t = 0.f;
  {
    int s = OFF[2 * N + i];
    int e = (i == N - 1) ? NG : OFF[2 * N + i + 1];
    for (int q = s; q < e; ++q) t += u_all[gIdx[q]];
  }
  float sc = 0.f;
  {
    int s = OFF[N + i];
    int e = (i == N - 1) ? NNZ : OFF[N + i + 1];
    for (int q = s; q < e; ++q) sc += csc_val[q] * Lv[csc_row[q]];
  }
  float Ap = Dall[i] * p[i] - t + rs_cm[i] * Lv[i] - sc;
  x[i] += alpha * p[i];
  float rn = r[i] - alpha * Ap;
  r[i] = rn;
  float v = blockReduce256(rn * rn);
  if (threadIdx.x == 0) atomicAdd(rs_t1, v);
}

__global__ void k_it3(float* __restrict__ p, const float* __restrict__ r,
                      const float* __restrict__ rs_new, const float* __restrict__ rs_old, int N)
{
  int i = blockIdx.x * TPB + threadIdx.x;
  float beta = rs_new[0] / rs_old[0];
  p[i] = r[i] + beta * p[i];
}

extern "C" void kernel_launch(void* const* d_in, const int* in_sizes, int n_in,
                              void* d_out, int out_size, void* d_ws, size_t ws_size,
                              hipStream_t stream)
{
  const float* CMw       = (const float*)d_in[0];
  const float* LOCw      = (const float*)d_in[1];
  const float* IUw       = (const float*)d_in[2];
  const float* KUw       = (const float*)d_in[3];
  const float* lmbda     = (const float*)d_in[4];
  const float* kToUconf  = (const float*)d_in[5];
  const float* known     = (const float*)d_in[6];
  const float* kToU      = (const float*)d_in[7];
  const float* Wcm_data  = (const float*)d_in[8];
  const float* LOC_flows = (const float*)d_in[9];
  const float* IU_flows  = (const float*)d_in[10];
  const int*   Wrow      = (const int*)d_in[11];
  const int*   Wcol      = (const int*)d_in[12];
  const int*   LOC_inInd = (const int*)d_in[13];
  const int*   IU_inInd  = (const int*)d_in[14];
  const int*   IU_neighInd = (const int*)d_in[15];
  const int*   width_p   = (const int*)d_in[16];
  const int CG_STEPS = 30;

  const int N    = in_sizes[0];      // 147456 (% 256 == 0)
  const int NNZ  = in_sizes[8];      // 1474560
  const int NLOC = in_sizes[13];     // 73728
  const int NG   = 19 * NLOC;

  float* x     = (float*)d_out;
  float* r     = (float*)d_ws;
  float* p     = r + N;
  float* Lv    = p + N;
  float* rs_cm = Lv + N;
  float* Dall  = rs_cm + N;
  float* u_all = Dall + N;                      // 19*NLOC
  float* csr_val = u_all + (size_t)NG;          // NNZ
  float* csc_val = csr_val + (size_t)NNZ;       // NNZ
  int*   csr_col = (int*)(csc_val + (size_t)NNZ);
  int*   csc_row = csr_col + (size_t)NNZ;
  int*   gIdx    = csc_row + (size_t)NNZ;       // 19*NLOC
  int*   CNT = gIdx + (size_t)NG;               // 3N
  int*   OFF = CNT + (size_t)3 * N;             // 3N
  int*   CUR = OFF + (size_t)3 * N;             // 3N
  int*   bsum = CUR + (size_t)3 * N;            // 3*(N/256)
  float* scal = (float*)(bsum + 3 * (N / TPB)); // rs at [t], pAp at [32+t]

  const int Bn = N / TPB;
  const int Bz = NNZ / TPB;
  const int Bl = NLOC / TPB;
  const int Z3 = 3 * Bn;

  k_init0<<<Z3, TPB, 0, stream>>>(KUw, kToUconf, lmbda, known, kToU,
                                  Dall, rs_cm, r, p, x, CNT, scal, N);
  k_hist<<<Bz + 2 * Bl + Bn, TPB, 0, stream>>>(
      CMw, Wcm_data, Wrow, Wcol, LOCw, LOC_flows, LOC_inInd, width_p,
      IUw, IU_flows, IU_inInd, IU_neighInd,
      rs_cm, Dall, CNT, r, scal, NNZ, NLOC, N, Bz, Bz + Bl, Bz + 2 * Bl);
  k_scan1<<<Z3, TPB, 0, stream>>>(CNT, OFF, bsum, 3 * N);
  k_scan2<<<3, 1024, 0, stream>>>(bsum, Bn);
  k_scan3<<<Z3, TPB, 0, stream>>>(OFF, CUR, bsum, 3 * N);
  k_fill<<<Bz + 2 * Bl, TPB, 0, stream>>>(
      CMw, Wcm_data, Wrow, Wcol, LOC_inInd, width_p, IU_inInd, IU_neighInd,
      CUR, csr_col, csr_val, csc_row, csc_val, gIdx, NNZ, NLOC, N, Bz, Bz + Bl);

  for (int t = 0; t < CG_STEPS; ++t) {
    k_it1<<<2 * Bl + Bn, TPB, 0, stream>>>(
        p, LOC_flows, LOC_inInd, LOCw, width_p,
        IU_flows, IU_inInd, IU_neighInd, IUw,
        rs_cm, Dall, OFF, csr_col, csr_val,
        u_all, Lv, scal + 32 + t, NNZ, NLOC, N, Bl, 2 * Bl);
    k_it2<<<Bn, TPB, 0, stream>>>(
        x, r, p, Lv, rs_cm, Dall, OFF, csc_row, csc_val, gIdx, u_all,
        scal + t, scal + 32 + t, scal + t + 1, NNZ, NG, N);
    if (t + 1 < CG_STEPS)
      k_it3<<<Bn, TPB, 0, stream>>>(p, r, scal + t + 1, scal + t, N);
  }
}